// Round 1
// baseline (6552.328 us; speedup 1.0000x reference)
//
#include <hip/hip_runtime.h>
#include <hip/hip_bf16.h>

#define N_NODES   100000
#define N_EDGES   1600000
#define EMB       128
#define HID       128
#define N_CLASSES 10
#define N_GRAPHS  512

// ---------------- degree / norm ----------------
__global__ __launch_bounds__(256) void k_deg_init(float* deg) {
    int i = blockIdx.x * 256 + threadIdx.x;
    if (i < N_NODES) deg[i] = 1.0f;  // self-loop
}

__global__ __launch_bounds__(256) void k_deg_acc(const int* __restrict__ dst, float* deg) {
    int e = blockIdx.x * 256 + threadIdx.x;
    if (e < N_EDGES) atomicAdd(&deg[dst[e]], 1.0f);
}

__global__ __launch_bounds__(256) void k_dinv(float* deg) {
    int i = blockIdx.x * 256 + threadIdx.x;
    if (i < N_NODES) deg[i] = rsqrtf(deg[i]);  // deg >= 1 always
}

// ---------------- embedding gather ----------------
__global__ __launch_bounds__(256) void k_gather(const int* __restrict__ idx,
                                                const float* __restrict__ emb,
                                                float* __restrict__ X) {
    int tid = blockIdx.x * 256 + threadIdx.x;
    if (tid >= N_NODES * 32) return;
    int v = tid >> 5, q = tid & 31;
    const float4* src = reinterpret_cast<const float4*>(emb + (size_t)idx[v] * EMB);
    reinterpret_cast<float4*>(X + (size_t)v * EMB)[q] = src[q];
}

// ---------------- dense GEMM: Y[n,128] = X[n,128] @ W[128,128] ----------------
// W staged in LDS (64 KB). 32 lanes per row, each lane computes 4 columns.
__global__ __launch_bounds__(256) void k_gemm128(const float* __restrict__ X,
                                                 const float* __restrict__ W,
                                                 float* __restrict__ Y, int nrows) {
    __shared__ float Ws[128 * 128];
    for (int i = threadIdx.x; i < 128 * 32; i += 256)
        reinterpret_cast<float4*>(Ws)[i] = reinterpret_cast<const float4*>(W)[i];
    __syncthreads();

    const int c = threadIdx.x & 31;   // column group (4 cols)
    const int rs = threadIdx.x >> 5;  // 0..7 row within block-iter

    for (int row = blockIdx.x * 8 + rs; row < nrows; row += gridDim.x * 8) {
        const float4* x4 = reinterpret_cast<const float4*>(X + (size_t)row * 128);
        float4 acc = {0.f, 0.f, 0.f, 0.f};
        #pragma unroll
        for (int k4 = 0; k4 < 32; ++k4) {
            float4 a = x4[k4];
            float4 w0 = reinterpret_cast<const float4*>(Ws + (k4 * 4 + 0) * 128)[c];
            float4 w1 = reinterpret_cast<const float4*>(Ws + (k4 * 4 + 1) * 128)[c];
            float4 w2 = reinterpret_cast<const float4*>(Ws + (k4 * 4 + 2) * 128)[c];
            float4 w3 = reinterpret_cast<const float4*>(Ws + (k4 * 4 + 3) * 128)[c];
            acc.x += a.x * w0.x + a.y * w1.x + a.z * w2.x + a.w * w3.x;
            acc.y += a.x * w0.y + a.y * w1.y + a.z * w2.y + a.w * w3.y;
            acc.z += a.x * w0.z + a.y * w1.z + a.z * w2.z + a.w * w3.z;
            acc.w += a.x * w0.w + a.y * w1.w + a.z * w2.w + a.w * w3.w;
        }
        reinterpret_cast<float4*>(Y + (size_t)row * 128)[c] = acc;
    }
}

// ---------------- self-loop init: AGG[v] = H[v] * dinv[v]^2 ----------------
__global__ __launch_bounds__(256) void k_selfinit(const float* __restrict__ H,
                                                  const float* __restrict__ dinv,
                                                  float* __restrict__ AGG) {
    int tid = blockIdx.x * 256 + threadIdx.x;
    if (tid >= N_NODES * 32) return;
    int v = tid >> 5, q = tid & 31;
    float s = dinv[v]; s = s * s;
    float4 h = reinterpret_cast<const float4*>(H + (size_t)v * 128)[q];
    float4 o = {h.x * s, h.y * s, h.z * s, h.w * s};
    reinterpret_cast<float4*>(AGG + (size_t)v * 128)[q] = o;
}

// ---------------- edge scatter: AGG[d] += H[s] * dinv[s]*dinv[d] ----------------
__global__ __launch_bounds__(256) void k_scatter(const int* __restrict__ src,
                                                 const int* __restrict__ dst,
                                                 const float* __restrict__ dinv,
                                                 const float* __restrict__ H,
                                                 float* __restrict__ AGG) {
    int tid = blockIdx.x * 256 + threadIdx.x;
    if (tid >= N_EDGES * 32) return;
    int e = tid >> 5, q = tid & 31;
    int s = src[e], d = dst[e];
    float norm = dinv[s] * dinv[d];
    float4 h = reinterpret_cast<const float4*>(H + (size_t)s * 128)[q];
    float* out = AGG + (size_t)d * 128 + q * 4;
    atomicAdd(out + 0, h.x * norm);
    atomicAdd(out + 1, h.y * norm);
    atomicAdd(out + 2, h.z * norm);
    atomicAdd(out + 3, h.w * norm);
}

// ---------------- bias + relu in place ----------------
__global__ __launch_bounds__(256) void k_bias_relu(float* __restrict__ X,
                                                   const float* __restrict__ b) {
    int tid = blockIdx.x * 256 + threadIdx.x;
    if (tid >= N_NODES * 32) return;
    int q = tid & 31;
    float4 v = reinterpret_cast<float4*>(X)[tid];
    const float4 bb = reinterpret_cast<const float4*>(b)[q];
    v.x = fmaxf(v.x + bb.x, 0.f);
    v.y = fmaxf(v.y + bb.y, 0.f);
    v.z = fmaxf(v.z + bb.z, 0.f);
    v.w = fmaxf(v.w + bb.w, 0.f);
    reinterpret_cast<float4*>(X)[tid] = v;
}

// ---------------- per-graph mean pool (batch sorted -> binary search) ----------------
__global__ __launch_bounds__(128) void k_pool(const float* __restrict__ X,
                                              const int* __restrict__ batch,
                                              float* __restrict__ psum,
                                              float* __restrict__ pcnt) {
    int g = blockIdx.x;
    // start = lower_bound(batch, g), end = lower_bound(batch, g+1)
    int lo = 0, hi = N_NODES;
    while (lo < hi) { int mid = (lo + hi) >> 1; if (batch[mid] < g) lo = mid + 1; else hi = mid; }
    int start = lo;
    hi = N_NODES;
    while (lo < hi) { int mid = (lo + hi) >> 1; if (batch[mid] < g + 1) lo = mid + 1; else hi = mid; }
    int end = lo;

    int c = threadIdx.x;
    float acc = 0.f;
    for (int n = start; n < end; ++n) acc += X[(size_t)n * 128 + c];
    psum[g * 128 + c] = acc;
    if (c == 0) pcnt[g] = (float)(end - start);
}

// ---------------- final linear on pooled means ----------------
__global__ __launch_bounds__(256) void k_final(const float* __restrict__ psum,
                                               const float* __restrict__ pcnt,
                                               const float* __restrict__ linW,
                                               const float* __restrict__ linb,
                                               float* __restrict__ out) {
    int tid = blockIdx.x * 256 + threadIdx.x;
    if (tid >= N_GRAPHS * N_CLASSES) return;
    int g = tid / N_CLASSES, c = tid % N_CLASSES;
    float acc = 0.f;
    #pragma unroll 8
    for (int k = 0; k < HID; ++k) acc += psum[g * 128 + k] * linW[k * N_CLASSES + c];
    float cnt = fmaxf(pcnt[g], 1.0f);
    out[tid] = acc / cnt + linb[c];
}

extern "C" void kernel_launch(void* const* d_in, const int* in_sizes, int n_in,
                              void* d_out, int out_size, void* d_ws, size_t ws_size,
                              hipStream_t stream) {
    const int*   x_idx = (const int*)d_in[0];
    const int*   eidx  = (const int*)d_in[1];
    const int*   batch = (const int*)d_in[2];
    const float* emb   = (const float*)d_in[3];
    const float* W1    = (const float*)d_in[4];
    const float* b1    = (const float*)d_in[5];
    const float* W2    = (const float*)d_in[6];
    const float* b2    = (const float*)d_in[7];
    const float* linW  = (const float*)d_in[8];
    const float* linb  = (const float*)d_in[9];
    float* out = (float*)d_out;

    const int* src = eidx;            // edge_index[0]
    const int* dst = eidx + N_EDGES;  // edge_index[1]

    float* A    = (float*)d_ws;                    // [N,128]
    float* B    = A + (size_t)N_NODES * 128;       // [N,128]
    float* dinv = B + (size_t)N_NODES * 128;       // [N]
    float* psum = dinv + N_NODES;                  // [G,128]
    float* pcnt = psum + N_GRAPHS * 128;           // [G]

    const int TPB = 256;
    const int gN    = (N_NODES + TPB - 1) / TPB;
    const int gE    = (N_EDGES + TPB - 1) / TPB;
    const int gN32  = (N_NODES * 32 + TPB - 1) / TPB;
    const int gE32  = (N_EDGES * 32 + TPB - 1) / TPB;

    // degree -> dinv
    k_deg_init<<<gN, TPB, 0, stream>>>(dinv);
    k_deg_acc<<<gE, TPB, 0, stream>>>(dst, dinv);
    k_dinv<<<gN, TPB, 0, stream>>>(dinv);

    // x = emb[x_idx]
    k_gather<<<gN32, TPB, 0, stream>>>(x_idx, emb, A);

    // ---- layer 1 ----
    k_gemm128<<<2048, TPB, 0, stream>>>(A, W1, B, N_NODES);
    k_selfinit<<<gN32, TPB, 0, stream>>>(B, dinv, A);
    k_scatter<<<gE32, TPB, 0, stream>>>(src, dst, dinv, B, A);
    k_bias_relu<<<gN32, TPB, 0, stream>>>(A, b1);

    // ---- layer 2 ----
    k_gemm128<<<2048, TPB, 0, stream>>>(A, W2, B, N_NODES);
    k_selfinit<<<gN32, TPB, 0, stream>>>(B, dinv, A);
    k_scatter<<<gE32, TPB, 0, stream>>>(src, dst, dinv, B, A);
    k_bias_relu<<<gN32, TPB, 0, stream>>>(A, b2);

    // ---- pool + final linear ----
    k_pool<<<N_GRAPHS, 128, 0, stream>>>(A, batch, psum, pcnt);
    k_final<<<(N_GRAPHS * N_CLASSES + TPB - 1) / TPB, TPB, 0, stream>>>(psum, pcnt, linW, linb, out);
}

// Round 2
// 1448.793 us; speedup vs baseline: 4.5226x; 4.5226x over previous
//
#include <hip/hip_runtime.h>
#include <hip/hip_bf16.h>

#define N_NODES   100000
#define N_EDGES   1600000
#define EMB       128
#define HID       128
#define N_CLASSES 10
#define N_GRAPHS  512

#define SCAN_ELEMS 1024
#define N_SCAN_BLKS ((N_NODES + SCAN_ELEMS - 1) / SCAN_ELEMS)  // 98

// ---------------- CSR build ----------------
__global__ __launch_bounds__(256) void k_zero_int(int* __restrict__ p, int n) {
    int i = blockIdx.x * 256 + threadIdx.x;
    if (i < n) p[i] = 0;
}

__global__ __launch_bounds__(256) void k_count(const int* __restrict__ dst, int* __restrict__ cnt) {
    int e = blockIdx.x * 256 + threadIdx.x;
    if (e < N_EDGES) atomicAdd(&cnt[dst[e]], 1);
}

// per-block sums of cnt in chunks of 1024
__global__ __launch_bounds__(256) void k_block_sums(const int* __restrict__ cnt, int* __restrict__ bsum) {
    __shared__ int sh[256];
    int b = blockIdx.x, t = threadIdx.x;
    int s = 0;
    #pragma unroll
    for (int k = 0; k < 4; ++k) {
        int i = b * SCAN_ELEMS + k * 256 + t;
        if (i < N_NODES) s += cnt[i];
    }
    sh[t] = s;
    __syncthreads();
    for (int off = 128; off; off >>= 1) {
        if (t < off) sh[t] += sh[t + off];
        __syncthreads();
    }
    if (t == 0) bsum[b] = sh[0];
}

// inclusive scan of bsum[nb] (nb <= 128), single block
__global__ __launch_bounds__(128) void k_scan_bsums(int* __restrict__ bsum, int nb) {
    __shared__ int sh[128];
    int t = threadIdx.x;
    sh[t] = (t < nb) ? bsum[t] : 0;
    __syncthreads();
    for (int off = 1; off < 128; off <<= 1) {
        int v = (t >= off) ? sh[t - off] : 0;
        __syncthreads();
        sh[t] += v;
        __syncthreads();
    }
    if (t < nb) bsum[t] = sh[t];
}

// final exclusive scan -> rowptr
__global__ __launch_bounds__(256) void k_scan_final(const int* __restrict__ cnt,
                                                    const int* __restrict__ bsum,
                                                    int* __restrict__ rowptr) {
    __shared__ int sh[256];
    int b = blockIdx.x, t = threadIdx.x;
    int base_i = b * SCAN_ELEMS + t * 4;
    int c0 = (base_i + 0 < N_NODES) ? cnt[base_i + 0] : 0;
    int c1 = (base_i + 1 < N_NODES) ? cnt[base_i + 1] : 0;
    int c2 = (base_i + 2 < N_NODES) ? cnt[base_i + 2] : 0;
    int c3 = (base_i + 3 < N_NODES) ? cnt[base_i + 3] : 0;
    int tsum = c0 + c1 + c2 + c3;
    sh[t] = tsum;
    __syncthreads();
    for (int off = 1; off < 256; off <<= 1) {
        int v = (t >= off) ? sh[t - off] : 0;
        __syncthreads();
        sh[t] += v;
        __syncthreads();
    }
    int base = ((b == 0) ? 0 : bsum[b - 1]) + (sh[t] - tsum);
    if (base_i + 0 < N_NODES) rowptr[base_i + 0] = base;          base += c0;
    if (base_i + 1 < N_NODES) rowptr[base_i + 1] = base;          base += c1;
    if (base_i + 2 < N_NODES) rowptr[base_i + 2] = base;          base += c2;
    if (base_i + 3 < N_NODES) rowptr[base_i + 3] = base;
    if (b == 0 && t == 0) rowptr[N_NODES] = N_EDGES;
}

__global__ __launch_bounds__(256) void k_dinv_from_rowptr(const int* __restrict__ rowptr,
                                                          float* __restrict__ dinv) {
    int i = blockIdx.x * 256 + threadIdx.x;
    if (i < N_NODES) dinv[i] = rsqrtf((float)(rowptr[i + 1] - rowptr[i] + 1));  // +1 self-loop
}

__global__ __launch_bounds__(256) void k_copy_int(const int* __restrict__ a, int* __restrict__ b, int n) {
    int i = blockIdx.x * 256 + threadIdx.x;
    if (i < n) b[i] = a[i];
}

__global__ __launch_bounds__(256) void k_fill(const int* __restrict__ src, const int* __restrict__ dst,
                                              int* __restrict__ cursor, int* __restrict__ col) {
    int e = blockIdx.x * 256 + threadIdx.x;
    if (e < N_EDGES) {
        int slot = atomicAdd(&cursor[dst[e]], 1);
        col[slot] = src[e];
    }
}

// ---------------- embedding gather ----------------
__global__ __launch_bounds__(256) void k_gather(const int* __restrict__ idx,
                                                const float* __restrict__ emb,
                                                float* __restrict__ X) {
    int tid = blockIdx.x * 256 + threadIdx.x;
    if (tid >= N_NODES * 32) return;
    int v = tid >> 5, q = tid & 31;
    const float4* s = reinterpret_cast<const float4*>(emb + (size_t)idx[v] * EMB);
    reinterpret_cast<float4*>(X + (size_t)v * EMB)[q] = s[q];
}

// ---------------- dense GEMM: Y[n] = (X[n] @ W) * dinv[n] ----------------
__global__ __launch_bounds__(256) void k_gemm128(const float* __restrict__ X,
                                                 const float* __restrict__ W,
                                                 const float* __restrict__ dinv,
                                                 float* __restrict__ Y, int nrows) {
    __shared__ float Ws[128 * 128];
    for (int i = threadIdx.x; i < 128 * 32; i += 256)
        reinterpret_cast<float4*>(Ws)[i] = reinterpret_cast<const float4*>(W)[i];
    __syncthreads();

    const int c = threadIdx.x & 31;
    const int rs = threadIdx.x >> 5;

    for (int row = blockIdx.x * 8 + rs; row < nrows; row += gridDim.x * 8) {
        const float4* x4 = reinterpret_cast<const float4*>(X + (size_t)row * 128);
        float4 acc = {0.f, 0.f, 0.f, 0.f};
        #pragma unroll
        for (int k4 = 0; k4 < 32; ++k4) {
            float4 a = x4[k4];
            float4 w0 = reinterpret_cast<const float4*>(Ws + (k4 * 4 + 0) * 128)[c];
            float4 w1 = reinterpret_cast<const float4*>(Ws + (k4 * 4 + 1) * 128)[c];
            float4 w2 = reinterpret_cast<const float4*>(Ws + (k4 * 4 + 2) * 128)[c];
            float4 w3 = reinterpret_cast<const float4*>(Ws + (k4 * 4 + 3) * 128)[c];
            acc.x += a.x * w0.x + a.y * w1.x + a.z * w2.x + a.w * w3.x;
            acc.y += a.x * w0.y + a.y * w1.y + a.z * w2.y + a.w * w3.y;
            acc.z += a.x * w0.z + a.y * w1.z + a.z * w2.z + a.w * w3.z;
            acc.w += a.x * w0.w + a.y * w1.w + a.z * w2.w + a.w * w3.w;
        }
        float dv = dinv[row];
        acc.x *= dv; acc.y *= dv; acc.z *= dv; acc.w *= dv;
        reinterpret_cast<float4*>(Y + (size_t)row * 128)[c] = acc;
    }
}

// ---------------- CSR aggregation: Out[d] = relu(dinv[d]*(B[d] + sum B[s]) + bias) ----------------
// One 64-lane wave per node; each lane owns 2 columns (float2).
__global__ __launch_bounds__(256) void k_aggregate(const float* __restrict__ B,
                                                   const int* __restrict__ rowptr,
                                                   const int* __restrict__ col,
                                                   const float* __restrict__ dinv,
                                                   const float* __restrict__ bias,
                                                   float* __restrict__ Out) {
    int v = (blockIdx.x * 256 + threadIdx.x) >> 6;
    int lane = threadIdx.x & 63;
    if (v >= N_NODES) return;
    int beg = rowptr[v], end = rowptr[v + 1];

    float2 acc = reinterpret_cast<const float2*>(B + (size_t)v * 128)[lane];  // self-loop seed
    int j = beg;
    for (; j + 1 < end; j += 2) {
        int s0 = col[j], s1 = col[j + 1];
        float2 h0 = reinterpret_cast<const float2*>(B + (size_t)s0 * 128)[lane];
        float2 h1 = reinterpret_cast<const float2*>(B + (size_t)s1 * 128)[lane];
        acc.x += h0.x + h1.x;
        acc.y += h0.y + h1.y;
    }
    if (j < end) {
        int s0 = col[j];
        float2 h0 = reinterpret_cast<const float2*>(B + (size_t)s0 * 128)[lane];
        acc.x += h0.x;
        acc.y += h0.y;
    }
    float dv = dinv[v];
    float2 bb = reinterpret_cast<const float2*>(bias)[lane];
    acc.x = fmaxf(acc.x * dv + bb.x, 0.f);
    acc.y = fmaxf(acc.y * dv + bb.y, 0.f);
    reinterpret_cast<float2*>(Out + (size_t)v * 128)[lane] = acc;
}

// ---------------- per-graph mean pool ----------------
__global__ __launch_bounds__(128) void k_pool(const float* __restrict__ X,
                                              const int* __restrict__ batch,
                                              float* __restrict__ psum,
                                              float* __restrict__ pcnt) {
    int g = blockIdx.x;
    int lo = 0, hi = N_NODES;
    while (lo < hi) { int mid = (lo + hi) >> 1; if (batch[mid] < g) lo = mid + 1; else hi = mid; }
    int start = lo;
    hi = N_NODES;
    while (lo < hi) { int mid = (lo + hi) >> 1; if (batch[mid] < g + 1) lo = mid + 1; else hi = mid; }
    int end = lo;

    int c = threadIdx.x;
    float acc = 0.f;
    for (int n = start; n < end; ++n) acc += X[(size_t)n * 128 + c];
    psum[g * 128 + c] = acc;
    if (c == 0) pcnt[g] = (float)(end - start);
}

// ---------------- final linear ----------------
__global__ __launch_bounds__(256) void k_final(const float* __restrict__ psum,
                                               const float* __restrict__ pcnt,
                                               const float* __restrict__ linW,
                                               const float* __restrict__ linb,
                                               float* __restrict__ out) {
    int tid = blockIdx.x * 256 + threadIdx.x;
    if (tid >= N_GRAPHS * N_CLASSES) return;
    int g = tid / N_CLASSES, c = tid % N_CLASSES;
    float acc = 0.f;
    #pragma unroll 8
    for (int k = 0; k < HID; ++k) acc += psum[g * 128 + k] * linW[k * N_CLASSES + c];
    float cnt = fmaxf(pcnt[g], 1.0f);
    out[tid] = acc / cnt + linb[c];
}

extern "C" void kernel_launch(void* const* d_in, const int* in_sizes, int n_in,
                              void* d_out, int out_size, void* d_ws, size_t ws_size,
                              hipStream_t stream) {
    const int*   x_idx = (const int*)d_in[0];
    const int*   eidx  = (const int*)d_in[1];
    const int*   batch = (const int*)d_in[2];
    const float* emb   = (const float*)d_in[3];
    const float* W1    = (const float*)d_in[4];
    const float* b1    = (const float*)d_in[5];
    const float* W2    = (const float*)d_in[6];
    const float* b2    = (const float*)d_in[7];
    const float* linW  = (const float*)d_in[8];
    const float* linb  = (const float*)d_in[9];
    float* out = (float*)d_out;

    const int* src = eidx;
    const int* dst = eidx + N_EDGES;

    // workspace layout (16B-aligned chunks first)
    char* w = (char*)d_ws;
    float* A      = (float*)w;  w += (size_t)N_NODES * 128 * 4;   // 51.2 MB
    float* Bm     = (float*)w;  w += (size_t)N_NODES * 128 * 4;   // 51.2 MB
    float* psum   = (float*)w;  w += (size_t)N_GRAPHS * 128 * 4;
    float* pcnt   = (float*)w;  w += (size_t)N_GRAPHS * 4;
    float* dinv   = (float*)w;  w += (size_t)N_NODES * 4;
    int*   rowptr = (int*)w;    w += (size_t)(N_NODES + 1) * 4;
    int*   cnt    = (int*)w;    w += (size_t)N_NODES * 4;
    int*   cursor = (int*)w;    w += (size_t)N_NODES * 4;
    int*   bsum   = (int*)w;    w += (size_t)128 * 4;
    int*   col    = (int*)w;    w += (size_t)N_EDGES * 4;         // 6.4 MB

    const int TPB = 256;
    const int gN   = (N_NODES + TPB - 1) / TPB;
    const int gE   = (N_EDGES + TPB - 1) / TPB;
    const int gN32 = (N_NODES * 32 + TPB - 1) / TPB;
    const int gW   = (N_NODES * 64 + TPB - 1) / TPB;  // one wave per node

    // ---- CSR build (once, reused by both layers) ----
    k_zero_int<<<gN, TPB, 0, stream>>>(cnt, N_NODES);
    k_count<<<gE, TPB, 0, stream>>>(dst, cnt);
    k_block_sums<<<N_SCAN_BLKS, TPB, 0, stream>>>(cnt, bsum);
    k_scan_bsums<<<1, 128, 0, stream>>>(bsum, N_SCAN_BLKS);
    k_scan_final<<<N_SCAN_BLKS, TPB, 0, stream>>>(cnt, bsum, rowptr);
    k_dinv_from_rowptr<<<gN, TPB, 0, stream>>>(rowptr, dinv);
    k_copy_int<<<gN, TPB, 0, stream>>>(rowptr, cursor, N_NODES);
    k_fill<<<gE, TPB, 0, stream>>>(src, dst, cursor, col);

    // ---- embedding ----
    k_gather<<<gN32, TPB, 0, stream>>>(x_idx, emb, A);

    // ---- layer 1 ----
    k_gemm128<<<2048, TPB, 0, stream>>>(A, W1, dinv, Bm, N_NODES);
    k_aggregate<<<gW, TPB, 0, stream>>>(Bm, rowptr, col, dinv, b1, A);

    // ---- layer 2 ----
    k_gemm128<<<2048, TPB, 0, stream>>>(A, W2, dinv, Bm, N_NODES);
    k_aggregate<<<gW, TPB, 0, stream>>>(Bm, rowptr, col, dinv, b2, A);

    // ---- pool + final ----
    k_pool<<<N_GRAPHS, 128, 0, stream>>>(A, batch, psum, pcnt);
    k_final<<<(N_GRAPHS * N_CLASSES + TPB - 1) / TPB, TPB, 0, stream>>>(psum, pcnt, linW, linb, out);
}